// Round 8
// baseline (682.899 us; speedup 1.0000x reference)
//
#include <hip/hip_runtime.h>
#include <hip/hip_fp16.h>
#include <cstdint>
#include <cstddef>

// x[512,4096] fp32 ; gate/up codes [11008,4096] i32 ; down codes [4096,11008] i32
// absmax blocks of 64 along K ; out [512,4096] fp32
//
// R7: (1) NF4 dequant fully in registers via v_perm_b32 byte-LUT (no LDS
// table, no bank conflicts — R6 was LDS-pipe-bound: ~250 LDS cyc/wave-iter
// vs 310 MFMA cyc/SIMD-round). (2) M-block = 512 (all tokens), 512-thread
// 8-wave blocks -> every code byte fetched from HBM exactly once (R6 paid
// 2x duplication). (3) Retained: lgkm-only barrier (VMEM in flight across
// iters), packed-A fragment loads from L2, codes prefetched 2+ iters ahead
// with HBM loads newest in issue order, compile-time dbuf slot indices.

using float4v = __attribute__((ext_vector_type(4))) float;
using half8   = __attribute__((ext_vector_type(8))) _Float16;

// NF4 codebook as f16 bit patterns (RNE from the fp32 table):
//  idx : 0      1      2      3      4      5      6      7
//        BC00   B992   B833   B652   B48D   B1EA   ADD4   0000
//  idx : 8      9      10     11     12     13     14     15
//        2D18   3126   33E0   3568   370D   3880   39C9   3C00
// lo-byte tables (entries 0-3 / 4-7 / 8-11 / 12-15):
#define TL0 0x52339200u
#define TL1 0x00D4EA8Du
#define TL2 0x68E02618u
#define TL3 0x00C9800Du
// hi-byte tables:
#define TH0 0xB6B8B9BCu
#define TH1 0x00ADB1B4u
#define TH2 0x3533312Du
#define TH3 0x3C393837u

// barrier that does NOT drain vmcnt: only LDS ordering (B-tile ds_writes).
// Safe: no global_load_lds; the only cross-wave data is the LDS B tile.
#define BARRIER() asm volatile("s_waitcnt lgkmcnt(0)\n\ts_barrier" ::: "memory")

// Packed A layout (M=512 fixed): element (m,k) at
//   (((k>>5)*32 + (m>>4))*64 + ((k>>3)&3)*16 + (m&15))*8 + (k&7)
// -> a wave's MFMA A-fragment (16 m x 32 k) is one 64-lane x 16B dense load.

// C[512 x N] = A_packed * dequant(codes[N x K])^T
// Block 512M x 64N, BK=64, 8 waves (wave tile 64x64, 4x4 MFMA 16x16x32 f16).
// ATOMIC=false: r2 selects gate/up matrix; C stored f16 PACKED.
// ATOMIC=true : r2 = K-chunk (split-K); fp32 atomicAdd into row-major outF.
template <bool ATOMIC>
__global__ __launch_bounds__(512, 2) void gemm_nf4(
    const __half* __restrict__ Apk,
    const int* __restrict__ c0, const float* __restrict__ am0,
    const int* __restrict__ c1, const float* __restrict__ am1,
    __half* __restrict__ o0, __half* __restrict__ o1,
    float* __restrict__ outF,
    int N, int K, int Kc, int Ntiles)
{
  __shared__ __half Bb[2][64 * 72];   // 18 KB double-buffered B tile (pad 72)

  const int tid  = threadIdx.x;
  const int lane = tid & 63;
  const int wave = tid >> 6;          // 0..7, each owns 64 M-rows

  const int bid = blockIdx.x;
  const int nt  = bid % Ntiles;
  const int r2  = bid / Ntiles;       // matrix select (gate/up) or K-chunk

  const int k0 = ATOMIC ? r2 * Kc : 0;
  const int nk = Kc >> 6;
  const int* codes  = (!ATOMIC && r2) ? c1 : c0;
  const float* amax = (!ATOMIC && r2) ? am1 : am0;
  __half* outH      = (!ATOMIC && r2) ? o1 : o0;

  const int col0 = nt * 64;
  const int Kb   = K >> 6;

  // code staging: thread -> (row bn = tid>>3 in 0..63, eighth bq = tid&7)
  // thread loads 8 codes (2 int4) per iter, all in one absmax block.
  const int bn = tid >> 3;
  const int bq = tid & 7;
  const int* cSrc    = codes + (size_t)(col0 + bn) * K + k0;
  const float* amSrc = amax + (size_t)(col0 + bn) * Kb + (k0 >> 6);

  // packed-A bases
  const int kb0 = k0 >> 5;
  const int mb0 = wave * 4;

  float4v acc[4][4];
  {
    float4v z = {0.f, 0.f, 0.f, 0.f};
    #pragma unroll
    for (int i = 0; i < 4; ++i)
      #pragma unroll
      for (int j = 0; j < 4; ++j) acc[i][j] = z;
  }

  int4  cr[2][2];      // compile-time slot indices everywhere (R4 lesson)
  float amr[2];
  half8 apf[2][8];     // both kk halves, prefetched one iter ahead

#define LOADC(S, KT)                                                            \
  { const int4* _p = (const int4*)(cSrc + (size_t)(KT) * 64 + bq * 8);          \
    cr[S][0] = _p[0]; cr[S][1] = _p[1];                                         \
    amr[S] = amSrc[KT]; }

// register NF4 dequant: 4 codes (int4 lanes, each 0..15) -> 4 scaled f16.
#define DEQ4(_c, _am2, _po0, _po1)                                              \
  { unsigned _u  = (unsigned)(_c).x | ((unsigned)(_c).y << 8) |                 \
                   ((unsigned)(_c).z << 16) | ((unsigned)(_c).w << 24);         \
    unsigned _u7 = _u & 0x07070707u;                                            \
    unsigned _m8 = ((_u >> 3) & 0x01010101u) * 0xFFu;                           \
    unsigned _loA = __builtin_amdgcn_perm(TL1, TL0, _u);                        \
    unsigned _loB = __builtin_amdgcn_perm(TL3, TL2, _u7);                       \
    unsigned _lo  = (_m8 & _loB) | (~_m8 & _loA);                               \
    unsigned _hiA = __builtin_amdgcn_perm(TH1, TH0, _u);                        \
    unsigned _hiB = __builtin_amdgcn_perm(TH3, TH2, _u7);                       \
    unsigned _hi  = (_m8 & _hiB) | (~_m8 & _hiA);                               \
    unsigned _q0  = __builtin_amdgcn_perm(_hi, _lo, 0x05010400u);               \
    unsigned _q1  = __builtin_amdgcn_perm(_hi, _lo, 0x07030602u);               \
    __half2 _h0 = __hmul2(*(const __half2*)&_q0, _am2);                        \
    __half2 _h1 = __hmul2(*(const __half2*)&_q1, _am2);                        \
    _po0 = *(const unsigned*)&_h0; _po1 = *(const unsigned*)&_h1; }

// dequant this thread's 8 codes of slot S -> one b128 LDS write.
#define DEQB(BUFI, S)                                                           \
  { const __half _ah = __float2half(amr[S]);                                    \
    const __half2 _am2 = __half2{_ah, _ah};                                     \
    uint4 _wv;                                                                  \
    DEQ4(cr[S][0], _am2, _wv.x, _wv.y);                                         \
    DEQ4(cr[S][1], _am2, _wv.z, _wv.w);                                         \
    *(uint4*)&Bb[BUFI][bn * 72 + bq * 8] = _wv; }

// load all 8 A-fragments of k-tile KT (kk=0 -> [0..3], kk=1 -> [4..7])
#define LOADA8(DST, KT)                                                         \
  { _Pragma("unroll")                                                           \
    for (int _i = 0; _i < 4; ++_i)                                              \
      DST[_i] = *(const half8*)(Apk +                                           \
        ((size_t)((kb0 + (KT) * 2) * 32 + mb0 + _i) * 64 + lane) * 8);          \
    _Pragma("unroll")                                                           \
    for (int _i = 0; _i < 4; ++_i)                                              \
      DST[4 + _i] = *(const half8*)(Apk +                                       \
        ((size_t)((kb0 + (KT) * 2 + 1) * 32 + mb0 + _i) * 64 + lane) * 8); }

  // ---- prologue: codes t=0 -> slot0, t=1 -> slot1 (slot = t&1)
  LOADC(0, 0);
  if (nk > 1) LOADC(1, 1);
  DEQB(0, 0);
  LOADA8(apf[0], 0);
  if (nk > 2) LOADC(0, 2);         // t=2 -> slot0; HBM loads newest
  BARRIER();                       // Bb[0] visible; vmem stays in flight

// S/NP literal 0/1. Issue order: dequant+LDS write -> L2 A-prefetch ->
// HBM codes (newest) -> ds_reads -> MFMA on iter-old apf[S] -> lgkm barrier.
#define BODY(KT, S, NP)                                                         \
  { if ((KT) + 1 < nk) {                                                        \
      DEQB(NP, NP);                            /* codes t=KT+1, aged ~2 iters */\
      LOADA8(apf[NP], (KT) + 1);               /* L2 A frags for next iter */   \
      if ((KT) + 3 < nk) LOADC(NP, (KT) + 3);  /* HBM codes LAST */             \
    }                                                                           \
    half8 bf[4];                                                                \
    _Pragma("unroll")                                                           \
    for (int _j = 0; _j < 4; ++_j)                                              \
      bf[_j] = *(const half8*)&Bb[S][(_j * 16 + (lane & 15)) * 72 + ((lane >> 4) << 3)]; \
    _Pragma("unroll")                                                           \
    for (int _i = 0; _i < 4; ++_i)                                              \
      _Pragma("unroll")                                                         \
      for (int _j = 0; _j < 4; ++_j)                                            \
        acc[_i][_j] = __builtin_amdgcn_mfma_f32_16x16x32_f16(apf[S][_i], bf[_j], acc[_i][_j], 0, 0, 0); \
    _Pragma("unroll")                                                           \
    for (int _j = 0; _j < 4; ++_j)                                              \
      bf[_j] = *(const half8*)&Bb[S][(_j * 16 + (lane & 15)) * 72 + 32 + ((lane >> 4) << 3)]; \
    _Pragma("unroll")                                                           \
    for (int _i = 0; _i < 4; ++_i)                                              \
      _Pragma("unroll")                                                         \
      for (int _j = 0; _j < 4; ++_j)                                            \
        acc[_i][_j] = __builtin_amdgcn_mfma_f32_16x16x32_f16(apf[S][4 + _i], bf[_j], acc[_i][_j], 0, 0, 0); \
    BARRIER(); }                               /* lgkm only — VMEM in flight */

  int kt = 0;
  while (kt + 2 <= nk) { BODY(kt, 0, 1); BODY(kt + 1, 1, 0); kt += 2; }
  if (kt < nk) BODY(kt, 0, 1);     // odd-nk tail (down: nk=43; 42&1==0 ✓)

  // ---- epilogue. C/D map: col = lane&15 (n), row = (lane>>4)*4 + reg (m)
  if (ATOMIC) {
    const int ccol0 = col0 + (lane & 15);
    const int crow0 = wave * 64 + ((lane >> 4) << 2);
    #pragma unroll
    for (int i = 0; i < 4; ++i)
      #pragma unroll
      for (int j = 0; j < 4; ++j)
        #pragma unroll
        for (int rr = 0; rr < 4; ++rr) {
          const size_t idx = (size_t)(crow0 + i * 16 + rr) * N + (ccol0 + j * 16);
          atomicAdd(&outF[idx], acc[i][j][rr]);
        }
  } else {
    // store C packed (m = token row, n = this GEMM's out col = down's K):
    //   (((n>>5)*32 + (m>>4))*64 + ((n>>3)&3)*16 + (m&15))*8 + (n&7)
    // Block region is dense 128 KB -> L2 merges the 2B stores.
    const int jj    = lane & 7;
    const int lb    = (lane >> 3) & 1;
    const int rbase = (lane >> 4) << 2;
    const int kb_c  = col0 >> 5;
    #pragma unroll
    for (int i = 0; i < 4; ++i) {
      const int mb = wave * 4 + i;
      #pragma unroll
      for (int j = 0; j < 4; ++j) {
        const int kb = kb_c + (j >> 1);
        const int lp = ((j & 1) * 2 + lb) * 16 + rbase;
        #pragma unroll
        for (int rr = 0; rr < 4; ++rr) {
          const size_t a = ((size_t)(kb * 32 + mb) * 64 + (lp + rr)) * 8 + jj;
          outH[a] = __float2half(acc[i][j][rr]);
        }
      }
    }
  }
#undef LOADC
#undef DEQ4
#undef DEQB
#undef LOADA8
#undef BODY
}

// x fp32 row-major [512][4096] -> packed f16 fragment layout.
__global__ void cast_pack_kernel(const float* __restrict__ x,
                                 __half* __restrict__ xp, int nGrp) {
  int pid = blockIdx.x * blockDim.x + threadIdx.x;   // one per 8 halfs
  if (pid >= nGrp) return;
  const int lane = pid & 63;
  const int grp  = pid >> 6;
  const int mb   = grp & 31;          // M=512 -> 32 m-tiles
  const int kb   = grp >> 5;
  const int m = mb * 16 + (lane & 15);
  const int k = kb * 32 + ((lane >> 4) << 3);
  const float4* src = (const float4*)(x + (size_t)m * 4096 + k);
  float4 v0 = src[0], v1 = src[1];
  __half2 h0 = __floats2half2_rn(v0.x, v0.y), h1 = __floats2half2_rn(v0.z, v0.w);
  __half2 h2 = __floats2half2_rn(v1.x, v1.y), h3 = __floats2half2_rn(v1.z, v1.w);
  uint4 o;
  o.x = *(const unsigned*)&h0; o.y = *(const unsigned*)&h1;
  o.z = *(const unsigned*)&h2; o.w = *(const unsigned*)&h3;
  ((uint4*)xp)[pid] = o;
}

// elementwise silu(g)*u — layout-agnostic (g,u share the packed layout).
__global__ void swiglu_kernel(const __half* __restrict__ g,
                              const __half* __restrict__ u,
                              __half* __restrict__ h, int n2) {
  int i = blockIdx.x * blockDim.x + threadIdx.x;
  if (i < n2) {
    float2 gf = __half22float2(((const __half2*)g)[i]);
    float2 uf = __half22float2(((const __half2*)u)[i]);
    float h0 = gf.x / (1.f + __expf(-gf.x)) * uf.x;
    float h1 = gf.y / (1.f + __expf(-gf.y)) * uf.y;
    ((__half2*)h)[i] = __floats2half2_rn(h0, h1);
  }
}

extern "C" void kernel_launch(void* const* d_in, const int* in_sizes, int n_in,
                              void* d_out, int out_size, void* d_ws, size_t ws_size,
                              hipStream_t stream)
{
  (void)in_sizes; (void)n_in; (void)ws_size;
  const float* x            = (const float*)d_in[0];
  const int*   gate_codes   = (const int*)d_in[1];
  const float* gate_absmax  = (const float*)d_in[2];
  const int*   up_codes     = (const int*)d_in[3];
  const float* up_absmax    = (const float*)d_in[4];
  const int*   down_codes   = (const int*)d_in[5];
  const float* down_absmax  = (const float*)d_in[6];
  float* out = (float*)d_out;

  // ws: xp 4MB | g 11.3MB | u 11.3MB   (h = silu(g)*u written in place over g)
  __half* xp = (__half*)d_ws;
  __half* g  = xp + (size_t)512 * 4096;
  __half* u  = g  + (size_t)512 * 11008;

  hipMemsetAsync(d_out, 0, (size_t)out_size * sizeof(float), stream);

  cast_pack_kernel<<<1024, 256, 0, stream>>>(x, xp, (512 * 4096) / 8);

  // fused gate+up: 172 Ntiles x 2 mats = 344 blocks of 512 thr (M-block=512)
  gemm_nf4<false><<<344, 512, 0, stream>>>(xp, gate_codes, gate_absmax,
                                           up_codes, up_absmax,
                                           g, u, nullptr,
                                           11008, 4096, 4096, 172);

  swiglu_kernel<<<11008, 256, 0, stream>>>(g, u, g, (512 * 11008) / 2);

  // down: out += h * Wd^T, split-K=4: 64 nt x 4 ks = 256 blocks
  gemm_nf4<true><<<256, 512, 0, stream>>>(g, down_codes, down_absmax,
                                          nullptr, nullptr, nullptr, nullptr,
                                          out, 4096, 11008, 2752, 64);
}